// Round 17
// baseline (356.864 us; speedup 1.0000x reference)
//
#include <hip/hip_runtime.h>
#include <hip/hip_bf16.h>
#include <math.h>

// Problem constants (hardcoded from reference)
constexpr int B_ = 4, N_ = 384, H_ = 256, NH_ = 8, DD_ = 32, L_ = 4;
constexpr int M_ = B_ * N_;          // 1536 node rows
constexpr float CUT = 5.0f;
constexpr float PI_ = 3.14159265358979323846f;
constexpr float INVSC = 0.17677669529663687f;  // 1/sqrt(32)
constexpr int TBL_N = 4096;
constexpr int TBL_STRIDE = 4098;

typedef __attribute__((ext_vector_type(8))) short short8;
typedef __attribute__((ext_vector_type(4))) float f32x4;
typedef __attribute__((ext_vector_type(4))) unsigned short u16x4;
using u16 = unsigned short;

__device__ __forceinline__ u16 f2b(float f) {
  __hip_bfloat16 h = __float2bfloat16(f);
  return *reinterpret_cast<u16*>(&h);
}
__device__ __forceinline__ float b2f(u16 u) {
  __hip_bfloat16 h;
  *reinterpret_cast<u16*>(&h) = u;
  return __bfloat162float(h);
}

__device__ __forceinline__ float wave_sum(float v) {
#pragma unroll
  for (int s = 1; s < 64; s <<= 1) v += __shfl_xor(v, s);
  return v;
}

// ---------------- device bodies ----------------

// per-edge bias (all 4 layers' tables), dist computed inline
__device__ __forceinline__ void bias_item(const float* __restrict__ pos,
                                          const float* __restrict__ mask,
                                          const float* __restrict__ tbl2,
                                          u16* __restrict__ biasb, int e) {
  int j = e % N_;
  int t = e / N_;
  int i = t % N_;
  int b = t / N_;
  float mi = mask[b * N_ + i], mj = mask[b * N_ + j];
  const float* pi = pos + (size_t)(b * N_ + i) * 3;
  const float* pj = pos + (size_t)(b * N_ + j) * 3;
  float dx = pi[0] - pj[0] + 1e-9f;
  float dy = pi[1] - pj[1] + 1e-9f;
  float dz = pi[2] - pj[2] + 1e-9f;
  float d = sqrtf(dx * dx + dy * dy + dz * dz);
  bool edge = (mi > 0.f && mj > 0.f) && (d <= CUT);
  size_t plane = (size_t)N_ * N_;
  size_t obase = (size_t)b * NH_ * plane + (size_t)i * N_ + j;
  size_t lstride = (size_t)B_ * NH_ * plane;
  if (edge) {
    int ixrow;
    float fr;
    if (i == j) {
      ixrow = TBL_N + 1;
      fr = 0.f;
    } else {
      float u = d * ((float)TBL_N / CUT);
      int ix = (int)u;
      ix = ix > TBL_N - 1 ? TBL_N - 1 : ix;
      fr = u - (float)ix;
      ixrow = ix;
    }
    const float4* r0 = (const float4*)(tbl2 + (size_t)ixrow * 32);
    const float4* r1 = (const float4*)(tbl2 + (size_t)(ixrow + 1) * 32);
    float4 a0[8], a1[8];
#pragma unroll
    for (int q = 0; q < 8; q++) {
      a0[q] = r0[q];
      a1[q] = r1[q];
    }
    float w0 = 1.f - fr;
#pragma unroll
    for (int q = 0; q < 8; q++) {
      float v0[4] = {a0[q].x, a0[q].y, a0[q].z, a0[q].w};
      float v1[4] = {a1[q].x, a1[q].y, a1[q].z, a1[q].w};
#pragma unroll
      for (int c = 0; c < 4; c++) {
        int lh = q * 4 + c;
        int l = lh >> 3, h = lh & 7;
        float v = v0[c] * w0 + v1[c] * fr;
        biasb[(size_t)l * lstride + obase + (size_t)h * plane] = f2b(v);
      }
    }
  } else {
#pragma unroll
    for (int lh = 0; lh < 32; lh++) {
      int l = lh >> 3, h = lh & 7;
      biasb[(size_t)l * lstride + obase + (size_t)h * plane] = 0xFF80;  // -inf
    }
  }
}

// ---------------- combined setup kernel ----------------
// blocks [0,260): bias-table; [260,2884): weight transposes; [2884,4420): embed+LN1(l0)
struct TrJob {
  const float* src;
  u16* dst;
  int K, N, nx, ny, nz, base, dstride;
};
struct TrJobs {
  TrJob j[7];
};
__global__ __launch_bounds__(256) void setup_all_k(TrJobs jobs,
                                                   const float* __restrict__ rb_w1,
                                                   const float* __restrict__ rb_b1,
                                                   const float* __restrict__ rb_w2,
                                                   const float* __restrict__ rb_b2,
                                                   float* __restrict__ tbl2,
                                                   const int* __restrict__ nidx,
                                                   const float* __restrict__ mask,
                                                   const float* __restrict__ emb,
                                                   float* __restrict__ X,
                                                   const float* __restrict__ l1g,
                                                   const float* __restrict__ l1b,
                                                   u16* __restrict__ HB) {
  __shared__ float sfA[64][32];
  __shared__ float hbA[64][260];
  __shared__ float t[32][33];
  __shared__ float sw[8];
  int bid = blockIdx.x;
  int tid = threadIdx.x;
  if (bid < 260) {
    constexpr int TT = 64;
    int l = bid / 65;
    int t0 = (bid % 65) * TT;
#pragma unroll
    for (int m = 0; m < 8; m++) {
      int idx = m * 256 + tid;
      int tl = idx >> 5, k = idx & 31;
      int tt = t0 + tl;
      float d = (tt <= TBL_N) ? (tt * (CUT / (float)TBL_N)) : 1.7320508075688772e-9f;
      float ang = PI_ * (k + 1) * d * (1.f / CUT);
      sfA[tl][k] = sinf(ang) / (d + 1e-6f);
    }
    __syncthreads();
    float w1c[32];
    const float* w1 = rb_w1 + (size_t)l * DD_ * H_;
#pragma unroll
    for (int k = 0; k < 32; k++) w1c[k] = w1[k * H_ + tid];
    float b1v = rb_b1[l * H_ + tid];
    for (int tl = 0; tl < TT; tl++) {
      float pre = b1v;
      const float4* sfp = (const float4*)sfA[tl];
#pragma unroll
      for (int kq = 0; kq < 8; kq++) {
        float4 s4 = sfp[kq];
        pre += s4.x * w1c[kq * 4] + s4.y * w1c[kq * 4 + 1] + s4.z * w1c[kq * 4 + 2] +
               s4.w * w1c[kq * 4 + 3];
      }
      hbA[tl][tid] = pre / (1.f + __expf(-pre));
    }
    __syncthreads();
    const float* w2 = rb_w2 + (size_t)l * H_ * NH_;
    int o = tid & 7;
    float b2v = rb_b2[l * NH_ + o];
#pragma unroll
    for (int half = 0; half < 2; half++) {
      int tl = (tid >> 3) + half * 32;
      float acc = b2v;
      const float4* hp = (const float4*)hbA[tl];
#pragma unroll 4
      for (int hq = 0; hq < 64; hq++) {
        float4 h4 = hp[hq];
        acc += h4.x * w2[(hq * 4 + 0) * NH_ + o] + h4.y * w2[(hq * 4 + 1) * NH_ + o] +
               h4.z * w2[(hq * 4 + 2) * NH_ + o] + h4.w * w2[(hq * 4 + 3) * NH_ + o];
      }
      int tt = t0 + tl;
      if (tt <= TBL_STRIDE) tbl2[(size_t)tt * 32 + l * NH_ + o] = acc;
    }
  } else if (bid < 2884) {
    int tb = bid - 260;
    int ji = 0;
#pragma unroll
    for (int q = 1; q < 7; q++)
      if (tb >= jobs.j[q].base) ji = q;
    const TrJob& J = jobs.j[ji];
    int local = tb - J.base;
    int z = local / (J.nx * J.ny);
    int r2 = local % (J.nx * J.ny);
    int ky = r2 / J.nx, kx = r2 % J.nx;
    int n0 = kx * 32, k0 = ky * 32;
    const float* s = J.src + (size_t)z * J.K * J.N;
    u16* d = J.dst + (size_t)z * J.dstride;
    int r = tid >> 3, c4 = (tid & 7) * 4;
    float4 v = *(const float4*)(s + (size_t)(k0 + r) * J.N + n0 + c4);
    t[r][c4 + 0] = v.x;
    t[r][c4 + 1] = v.y;
    t[r][c4 + 2] = v.z;
    t[r][c4 + 3] = v.w;
    __syncthreads();
    u16x4 o;
    o[0] = f2b(t[c4 + 0][r]);
    o[1] = f2b(t[c4 + 1][r]);
    o[2] = f2b(t[c4 + 2][r]);
    o[3] = f2b(t[c4 + 3][r]);
    *(u16x4*)(d + (size_t)(n0 + r) * J.K + k0 + c4) = o;
  } else {
    // ---- embed + LN1(layer0): one row per block ----
    int row = bid - 2884;
    float mb = mask[row] > 0.f ? 1.f : 0.f;
    float v = emb[nidx[row] * H_ + tid] * mb;
    X[(size_t)row * H_ + tid] = v;
    float s = wave_sum(v);
    float q = wave_sum(v * v);
    int wv = tid >> 6, ln = tid & 63;
    if (ln == 0) {
      sw[wv] = s;
      sw[4 + wv] = q;
    }
    __syncthreads();
    float ts = sw[0] + sw[1] + sw[2] + sw[3];
    float tq = sw[4] + sw[5] + sw[6] + sw[7];
    float m = ts * (1.f / 256.f);
    float rs = rsqrtf(tq * (1.f / 256.f) - m * m + 1e-5f);
    HB[(size_t)row * H_ + tid] = f2b((v - m) * rs * l1g[tid] + l1b[tid]);
  }
}

// ---------------- bf16 MFMA GEMM body (device) ----------------
// C[M,Nc] = act(A'[M,K] @ W[K,Nc] + bias) (+resid); A' = PRE ? bf16(Af32*sigmoid(G)) : A
// ACT: 0 none, 1 silu, 2 gelu, 3 = plain bias col<768 / silu+bias2 col>=768.
template <int ACT, bool RES, bool PRE, bool OBF>
__device__ __forceinline__ void mgemm_body(u16* __restrict__ As, u16* __restrict__ Bs,
                                           const void* __restrict__ Av,
                                           const u16* __restrict__ WT,
                                           const float* __restrict__ bias,
                                           const float* __restrict__ resid,
                                           void* __restrict__ Cv, int K, int Nc,
                                           int lda, const float* __restrict__ G,
                                           const float* __restrict__ bias2,
                                           int m0, int n0) {
  const int tid = threadIdx.x;
  const int wave = tid >> 6, lane = tid & 63;
  const int wr = wave >> 1, wc = wave & 1, lr = lane & 15, lg = lane >> 4;
  f32x4 acc[2][2] = {};
  const int srow = tid >> 2, sp = tid & 3;
  for (int k0 = 0; k0 < K; k0 += 128) {
#pragma unroll
    for (int s4 = 0; s4 < 4; s4++) {
      int s = sp * 4 + s4;
      int phys = s ^ (srow & 15);
      if (PRE) {
        const float* ap = (const float*)Av + (size_t)(m0 + srow) * lda + k0 + s * 8;
        const float* gp = G + (size_t)(m0 + srow) * lda + k0 + s * 8;
        float4 a0 = *(const float4*)ap;
        float4 a1 = *(const float4*)(ap + 4);
        float4 g0 = *(const float4*)gp;
        float4 g1 = *(const float4*)(gp + 4);
        short8 vv;
        vv[0] = (short)f2b(a0.x / (1.f + __expf(-g0.x)));
        vv[1] = (short)f2b(a0.y / (1.f + __expf(-g0.y)));
        vv[2] = (short)f2b(a0.z / (1.f + __expf(-g0.z)));
        vv[3] = (short)f2b(a0.w / (1.f + __expf(-g0.w)));
        vv[4] = (short)f2b(a1.x / (1.f + __expf(-g1.x)));
        vv[5] = (short)f2b(a1.y / (1.f + __expf(-g1.y)));
        vv[6] = (short)f2b(a1.z / (1.f + __expf(-g1.z)));
        vv[7] = (short)f2b(a1.w / (1.f + __expf(-g1.w)));
        *(short8*)&As[srow * 128 + phys * 8] = vv;
      } else {
        const u16* Ab = (const u16*)Av;
        short8 v = *(const short8*)(Ab + (size_t)(m0 + srow) * lda + k0 + s * 8);
        *(short8*)&As[srow * 128 + phys * 8] = v;
      }
      short8 w = *(const short8*)(WT + (size_t)(n0 + srow) * K + k0 + s * 8);
      *(short8*)&Bs[srow * 128 + phys * 8] = w;
    }
    __syncthreads();
#pragma unroll
    for (int kk = 0; kk < 4; kk++) {
      int slot = kk * 4 + lg;
      short8 af[2], bf_[2];
#pragma unroll
      for (int i = 0; i < 2; i++) {
        int row = wr * 32 + i * 16 + lr;
        af[i] = *(const short8*)&As[row * 128 + (slot ^ (row & 15)) * 8];
      }
#pragma unroll
      for (int j = 0; j < 2; j++) {
        int row = wc * 32 + j * 16 + lr;
        bf_[j] = *(const short8*)&Bs[row * 128 + (slot ^ (row & 15)) * 8];
      }
#pragma unroll
      for (int i = 0; i < 2; i++)
#pragma unroll
        for (int j = 0; j < 2; j++)
          acc[i][j] = __builtin_amdgcn_mfma_f32_16x16x32_bf16(af[i], bf_[j], acc[i][j], 0, 0, 0);
    }
    __syncthreads();
  }
#pragma unroll
  for (int i = 0; i < 2; i++)
#pragma unroll
    for (int j = 0; j < 2; j++)
#pragma unroll
      for (int rg = 0; rg < 4; rg++) {
        int row = m0 + wr * 32 + i * 16 + lg * 4 + rg;
        int col = n0 + wc * 32 + j * 16 + lr;
        float v;
        if (ACT == 3) {
          float bv = (col < 768) ? bias[col] : bias2[col - 768];
          v = acc[i][j][rg] + bv;
          if (col >= 768) v = v / (1.f + __expf(-v));
        } else {
          v = acc[i][j][rg] + bias[col];
          if (ACT == 1) v = v / (1.f + __expf(-v));
          if (ACT == 2) v = 0.5f * v * (1.f + erff(v * 0.70710678118654752f));
        }
        if (RES) v += resid[(size_t)row * Nc + col];
        if (OBF)
          ((u16*)Cv)[(size_t)row * Nc + col] = f2b(v);
        else
          ((float*)Cv)[(size_t)row * Nc + col] = v;
      }
}

template <int ACT, bool RES, bool PRE, bool OBF>
__global__ __launch_bounds__(256) void mgemm_k(const void* __restrict__ Av,
                                               const u16* __restrict__ WT,
                                               const float* __restrict__ bias,
                                               const float* __restrict__ resid,
                                               void* __restrict__ Cv, int K, int Nc,
                                               int lda, const float* __restrict__ G,
                                               const float* __restrict__ bias2) {
  __shared__ u16 As[64 * 128];
  __shared__ u16 Bs[64 * 128];
  mgemm_body<ACT, RES, PRE, OBF>(As, Bs, Av, WT, bias, resid, Cv, K, Nc, lda, G, bias2,
                                 blockIdx.y * 64, blockIdx.x * 64);
}

// ---------------- full-width GEMM + residual + LN epilogue ----------------
// grid = 24 blocks; block computes 64-row x 256-col panel:
//   xnew = x + A'@W + bias  (A' = PRE ? bf16(ctx*sigmoid(G)) : ffb)
//   writes xnew (f32) and hb = bf16(LN(xnew; lng,lnb)).
// Wave w owns rows 16w..16w+15 (all 256 cols, 16 col-tiles) -> full rows in regs,
// LN stats via 4x shfl_xor over the 16-lane col dimension.
template <bool PRE>
__global__ __launch_bounds__(256) void glngemm_k(const void* __restrict__ Av,
                                                 const u16* __restrict__ WT,
                                                 const float* __restrict__ bias,
                                                 const float* __restrict__ G,
                                                 float* __restrict__ Xio,
                                                 u16* __restrict__ hb,
                                                 const float* __restrict__ lng,
                                                 const float* __restrict__ lnb,
                                                 int K, int lda) {
  __shared__ u16 As[64 * 64];   // 8 KB
  __shared__ u16 Bs[256 * 64];  // 32 KB
  const int m0 = blockIdx.x * 64;
  const int tid = threadIdx.x;
  const int wave = tid >> 6, lane = tid & 63;
  const int lr = lane & 15, lg = lane >> 4;
  f32x4 acc[16] = {};
  const int srow = tid >> 2, sp = tid & 3;
  for (int k0 = 0; k0 < K; k0 += 64) {
#pragma unroll
    for (int s2 = 0; s2 < 2; s2++) {
      int s = sp * 2 + s2;
      int phys = s ^ (srow & 7);
      if (PRE) {
        const float* ap = (const float*)Av + (size_t)(m0 + srow) * lda + k0 + s * 8;
        const float* gp = G + (size_t)(m0 + srow) * lda + k0 + s * 8;
        short8 vv;
#pragma unroll
        for (int q = 0; q < 8; q++) {
          vv[q] = (short)f2b(ap[q] / (1.f + __expf(-gp[q])));
        }
        *(short8*)&As[srow * 64 + phys * 8] = vv;
      } else {
        short8 v = *(const short8*)((const u16*)Av + (size_t)(m0 + srow) * lda + k0 + s * 8);
        *(short8*)&As[srow * 64 + phys * 8] = v;
      }
    }
    {
      const u16* wr_ = WT + (size_t)tid * K + k0;
#pragma unroll
      for (int s = 0; s < 8; s++) {
        int phys = s ^ (tid & 7);
        *(short8*)&Bs[tid * 64 + phys * 8] = *(const short8*)(wr_ + s * 8);
      }
    }
    __syncthreads();
#pragma unroll
    for (int grp = 0; grp < 2; grp++) {
      int arow = wave * 16 + lr;
      int achunk = (grp * 4 + lg) ^ (arow & 7);
      short8 af = *(const short8*)&As[arow * 64 + achunk * 8];
#pragma unroll
      for (int t = 0; t < 16; t++) {
        int brow = t * 16 + lr;
        int bchunk = (grp * 4 + lg) ^ (brow & 7);
        short8 bf = *(const short8*)&Bs[brow * 64 + bchunk * 8];
        acc[t] = __builtin_amdgcn_mfma_f32_16x16x32_bf16(af, bf, acc[t], 0, 0, 0);
      }
    }
    __syncthreads();
  }
  // epilogue: bias + resid -> x; then row LN -> hb
#pragma unroll
  for (int t = 0; t < 16; t++) {
    int col = t * 16 + lr;
    float bv = bias[col];
#pragma unroll
    for (int reg = 0; reg < 4; reg++) {
      int row = m0 + wave * 16 + lg * 4 + reg;
      float v = acc[t][reg] + bv + Xio[(size_t)row * 256 + col];
      acc[t][reg] = v;
      Xio[(size_t)row * 256 + col] = v;
    }
  }
  float sum[4] = {}, sq[4] = {};
#pragma unroll
  for (int t = 0; t < 16; t++)
#pragma unroll
    for (int reg = 0; reg < 4; reg++) {
      float v = acc[t][reg];
      sum[reg] += v;
      sq[reg] += v * v;
    }
#pragma unroll
  for (int reg = 0; reg < 4; reg++) {
#pragma unroll
    for (int s = 1; s < 16; s <<= 1) {
      sum[reg] += __shfl_xor(sum[reg], s);
      sq[reg] += __shfl_xor(sq[reg], s);
    }
  }
  float mean[4], rstd[4];
#pragma unroll
  for (int reg = 0; reg < 4; reg++) {
    mean[reg] = sum[reg] * (1.f / 256.f);
    rstd[reg] = rsqrtf(sq[reg] * (1.f / 256.f) - mean[reg] * mean[reg] + 1e-5f);
  }
#pragma unroll
  for (int t = 0; t < 16; t++) {
    int col = t * 16 + lr;
    float gg = lng[col], bb = lnb[col];
#pragma unroll
    for (int reg = 0; reg < 4; reg++) {
      int row = m0 + wave * 16 + lg * 4 + reg;
      hb[(size_t)row * 256 + col] = f2b((acc[t][reg] - mean[reg]) * rstd[reg] * gg + bb);
    }
  }
}

// ---------------- layer-0 qkv-gate GEMM + bias-tensor build (one launch) ----------
__global__ __launch_bounds__(256) void qkv_bias_k(const u16* __restrict__ hb,
                                                  const u16* __restrict__ wqg,
                                                  const float* __restrict__ qb,
                                                  const float* __restrict__ gb1,
                                                  u16* __restrict__ qgb,
                                                  const float* __restrict__ pos,
                                                  const float* __restrict__ mask,
                                                  const float* __restrict__ tbl2,
                                                  u16* __restrict__ biasb) {
  __shared__ u16 As[64 * 128];
  __shared__ u16 Bs[64 * 128];
  int bid = blockIdx.x;
  if (bid < 384) {
    mgemm_body<3, false, false, true>(As, Bs, hb, wqg, qb, nullptr, qgb, 256, 1024, 256,
                                      nullptr, gb1, (bid >> 4) * 64, (bid & 15) * 64);
  } else {
    bias_item(pos, mask, tbl2, biasb, (bid - 384) * 256 + threadIdx.x);
  }
}

// ---------------- MFMA fused attention body (device) ----------------
__device__ __forceinline__ void attn_body(u16* __restrict__ FragQ, u16* __restrict__ FragK,
                                          u16* __restrict__ FragV, float* __restrict__ smax,
                                          float* __restrict__ ssum,
                                          const u16* __restrict__ qkv,
                                          const u16* __restrict__ biasb,
                                          float* __restrict__ ctx, int qs,
                                          int it, int hh, int b) {
  u16* FragP = FragK;
  float* pbuf = (float*)FragV;
  const int i0 = it * 32;
  const int tid = threadIdx.x;
  const size_t bb = (size_t)b * N_;

  if (tid < 128) {
    int q = tid >> 2, dc = tid & 3;
    short8 v = *(const short8*)(qkv + (bb + i0 + q) * qs + hh * 32 + dc * 8);
    *(short8*)&FragQ[(((q >> 4) * 64) + (q & 15) + 16 * dc) * 8] = v;
  }
#pragma unroll
  for (int m = 0; m < 6; m++) {
    int idx = m * 256 + tid;
    int key = idx >> 2, dc = idx & 3;
    const u16* kb = qkv + (bb + key) * qs + 256 + hh * 32 + dc * 8;
    short8 kv = *(const short8*)kb;
    *(short8*)&FragK[(((key >> 4) * 64) + (key & 15) + 16 * dc) * 8] = kv;
    short8 vv = *(const short8*)(kb + 256);
    int kc = key >> 5, sub = (key >> 3) & 3, kj = key & 7;
#pragma unroll
    for (int j = 0; j < 8; j++) {
      int d = dc * 8 + j;
      FragV[(((kc * 2 + (d >> 4)) * 64) + (d & 15) + 16 * sub) * 8 + kj] = (u16)vv[j];
    }
  }
  __syncthreads();  // #0

  const int wave = tid >> 6, lane = tid & 63;
  const int rh = wave & 1, kh = wave >> 1;
  const int g = lane >> 4, c = lane & 15;
  const u16* bptr = biasb + (size_t)(b * NH_ + hh) * N_ * N_;

  short8 qf = *(const short8*)&FragQ[(rh * 64 + lane) * 8];
  f32x4 sc[12];
#pragma unroll
  for (int t = 0; t < 12; t++) {
    int T = kh * 12 + t;
    short8 kf = *(const short8*)&FragK[(T * 64 + lane) * 8];
    f32x4 z = {0.f, 0.f, 0.f, 0.f};
    sc[t] = __builtin_amdgcn_mfma_f32_16x16x32_bf16(qf, kf, z, 0, 0, 0);
    int key = 16 * T + c;
#pragma unroll
    for (int reg = 0; reg < 4; reg++) {
      int row = i0 + 16 * rh + 4 * g + reg;
      float bv = b2f(bptr[(size_t)row * N_ + key]);
      sc[t][reg] = sc[t][reg] * INVSC + bv;
    }
  }
  float mx[4];
#pragma unroll
  for (int reg = 0; reg < 4; reg++) {
    float m = sc[0][reg];
#pragma unroll
    for (int t = 1; t < 12; t++) m = fmaxf(m, sc[t][reg]);
#pragma unroll
    for (int s = 1; s < 16; s <<= 1) m = fmaxf(m, __shfl_xor(m, s));
    mx[reg] = m;
  }
  if (c == 0) {
#pragma unroll
    for (int reg = 0; reg < 4; reg++) smax[kh * 32 + 16 * rh + 4 * g + reg] = mx[reg];
  }
  __syncthreads();  // #1
  float sm[4];
#pragma unroll
  for (int reg = 0; reg < 4; reg++) {
    float M = fmaxf(smax[16 * rh + 4 * g + reg], smax[32 + 16 * rh + 4 * g + reg]);
    float s = 0.f;
#pragma unroll
    for (int t = 0; t < 12; t++) {
      float p = __expf(sc[t][reg] - M);
      sc[t][reg] = p;
      s += p;
    }
    sm[reg] = s;
  }
#pragma unroll
  for (int reg = 0; reg < 4; reg++) {
#pragma unroll
    for (int s = 1; s < 16; s <<= 1) sm[reg] += __shfl_xor(sm[reg], s);
  }
  if (c == 0) {
#pragma unroll
    for (int reg = 0; reg < 4; reg++) ssum[kh * 32 + 16 * rh + 4 * g + reg] = sm[reg];
  }
#pragma unroll
  for (int t = 0; t < 12; t++) {
    int T = kh * 12 + t;
    int kc = T >> 1;
    int sub = (2 * T + (c >> 3)) & 3;
#pragma unroll
    for (int reg = 0; reg < 4; reg++) {
      FragP[((rh * 12 + kc) * 64 + (4 * g + reg) + 16 * sub) * 8 + (c & 7)] =
          f2b(sc[t][reg]);
    }
  }
  __syncthreads();  // #2
  float Ls[4];
#pragma unroll
  for (int reg = 0; reg < 4; reg++)
    Ls[reg] = ssum[16 * rh + 4 * g + reg] + ssum[32 + 16 * rh + 4 * g + reg];

  f32x4 pcc[2] = {};
#pragma unroll
  for (int t = 0; t < 6; t++) {
    int kc = kh * 6 + t;
    short8 pf = *(const short8*)&FragP[((rh * 12 + kc) * 64 + lane) * 8];
#pragma unroll
    for (int nh = 0; nh < 2; nh++) {
      short8 vf = *(const short8*)&FragV[((kc * 2 + nh) * 64 + lane) * 8];
      pcc[nh] = __builtin_amdgcn_mfma_f32_16x16x32_bf16(pf, vf, pcc[nh], 0, 0, 0);
    }
  }
  __syncthreads();  // #3
  if (kh == 1) {
#pragma unroll
    for (int nh = 0; nh < 2; nh++)
#pragma unroll
      for (int reg = 0; reg < 4; reg++)
        pbuf[rh * 512 + (4 * g + reg) * 32 + nh * 16 + c] = pcc[nh][reg];
  }
  __syncthreads();  // #4
  if (kh == 0) {
#pragma unroll
    for (int nh = 0; nh < 2; nh++)
#pragma unroll
      for (int reg = 0; reg < 4; reg++) {
        float v = pcc[nh][reg] + pbuf[rh * 512 + (4 * g + reg) * 32 + nh * 16 + c];
        int row = i0 + 16 * rh + 4 * g + reg;
        ctx[(bb + row) * H_ + hh * 32 + nh * 16 + c] = v / Ls[reg];
      }
  }
}

// ---------------- merged attention + gate2-GEMM launch ----------------
__global__ __launch_bounds__(256) void attn_g2_k(const u16* __restrict__ qkv,
                                                 const u16* __restrict__ biasb,
                                                 float* __restrict__ ctx,
                                                 const u16* __restrict__ wg2,
                                                 const float* __restrict__ gb2,
                                                 float* __restrict__ g2) {
  __shared__ __align__(16) u16 SMEM[(2 + 24 + 24) * 64 * 8];  // 50 KB
  __shared__ float sred[2 * 32 * 2];                          // smax | ssum
  int bid = blockIdx.x;
  if (bid < 384) {
    int it = bid % 12;
    int t = bid / 12;
    attn_body(SMEM, SMEM + 1024, SMEM + 1024 + 12288, sred, sred + 64,
              qkv, biasb, ctx, 1024, it, t % NH_, t / NH_);
  } else {
    int g = bid - 384;  // 0..95 ; n0 = (g&3)*64, m0 = (g>>2)*64
    mgemm_body<0, false, false, false>(SMEM, SMEM + 8192, (const void*)(qkv + 768), wg2,
                                       gb2, nullptr, g2, 256, 256, 1024, nullptr,
                                       nullptr, (g >> 2) * 64, (g & 3) * 64);
  }
}

// ---------------- energy: masked mean over nodes then dot with eh_w ----------------
__global__ __launch_bounds__(256) void energy_k(const float* __restrict__ p2,
                                                const float* __restrict__ mask,
                                                const float* __restrict__ ehw,
                                                const float* __restrict__ ehb,
                                                float* __restrict__ out) {
  int b = blockIdx.x, h = threadIdx.x;
  float s = 0.f, cnt = 0.f;
#pragma unroll 4
  for (int i = 0; i < N_; i++) {
    float m = mask[b * N_ + i] > 0.f ? 1.f : 0.f;
    s += p2[(size_t)(b * N_ + i) * H_ + h] * m;
    cnt += m;
  }
  float val = s * ehw[h];
  __shared__ float red[256];
  red[h] = val;
  __syncthreads();
  for (int st = 128; st > 0; st >>= 1) {
    if (h < st) red[h] += red[h + st];
    __syncthreads();
  }
  if (h == 0) {
    float c = cnt < 1.f ? 1.f : cnt;
    out[b] = red[0] / c + ehb[0];
  }
}

extern "C" void kernel_launch(void* const* d_in, const int* in_sizes, int n_in,
                              void* d_out, int out_size, void* d_ws, size_t ws_size,
                              hipStream_t stream) {
  const int* node_idx = (const int*)d_in[0];
  const float* positions = (const float*)d_in[1];
  const float* mask = (const float*)d_in[2];
  const float* emb = (const float*)d_in[3];
  const float* ln1_g = (const float*)d_in[4];
  const float* ln1_b = (const float*)d_in[5];
  const float* qkv_w = (const float*)d_in[6];
  const float* qkv_b = (const float*)d_in[7];
  const float* out_w = (const float*)d_in[8];
  const float* out_b = (const float*)d_in[9];
  const float* rb_w1 = (const float*)d_in[10];
  const float* rb_b1 = (const float*)d_in[11];
  const float* rb_w2 = (const float*)d_in[12];
  const float* rb_b2 = (const float*)d_in[13];
  const float* gate_w1 = (const float*)d_in[14];
  const float* gate_b1 = (const float*)d_in[15];
  const float* gate_w2 = (const float*)d_in[16];
  const float* gate_b2 = (const float*)d_in[17];
  const float* ln2_g = (const float*)d_in[18];
  const float* ln2_b = (const float*)d_in[19];
  const float* ff_w1 = (const float*)d_in[20];
  const float* ff_b1 = (const float*)d_in[21];
  const float* ff_w2 = (const float*)d_in[22];
  const float* ff_b2 = (const float*)d_in[23];
  const float* pool_g = (const float*)d_in[24];
  const float* pool_beta = (const float*)d_in[25];
  const float* pool_w = (const float*)d_in[26];
  const float* pool_b = (const float*)d_in[27];
  const float* eh_w = (const float*)d_in[28];
  const float* eh_b = (const float*)d_in[29];
  float* eout = (float*)d_out;

  // workspace layout (bytes)
  char* W8 = (char*)d_ws;
  float* x = (float*)(W8 + 0);              // 1572864 B (M x 256 f32)
  u16* qgb = (u16*)(W8 + 1572864);          // 3145728 B (M x 1024 bf16: q|k|v|g1)
  float* ctx = (float*)(W8 + 4718592);      // 1572864 B
  float* g2 = (float*)(W8 + 6291456);       // 1572864 B
  u16* hb = (u16*)(W8 + 7864320);           // 786432 B  (M x 256 bf16)
  u16* ffb = (u16*)(W8 + 8650752);          // 1572864 B (M x 512 bf16)
  float* tbl2 = (float*)(W8 + 12582912);    // 524672 B (t-major)
  u16* wt = (u16*)(W8 + 13631488);          // 5373952 B
  u16* wt_qg = wt;                  // 4 x 1024 x 256
  u16* wt_out = wt + 1048576;       // 4 x 256 x 256
  u16* wt_g2 = wt + 1310720;
  u16* wt_f1 = wt + 1572864;        // 4 x 512 x 256
  u16* wt_f2 = wt + 2097152;        // 4 x 256 x 512
  u16* wt_p = wt + 2621440;         // 256 x 256
  u16* biasb = (u16*)(W8 + 19005440);       // 4 x 9437184 B ([l][b][h][i][j] bf16)
  const size_t bias_lstride = (size_t)B_ * NH_ * N_ * N_;

  // ---- setup: table + transposes + embed+LN1(l0) in ONE launch ----
  {
    TrJobs jobs;
    jobs.j[0] = {qkv_w, wt_qg, 256, 768, 24, 8, 4, 0, 262144};
    jobs.j[1] = {gate_w1, wt_qg + 768 * 256, 256, 256, 8, 8, 4, 768, 262144};
    jobs.j[2] = {out_w, wt_out, 256, 256, 8, 8, 4, 1024, 65536};
    jobs.j[3] = {gate_w2, wt_g2, 256, 256, 8, 8, 4, 1280, 65536};
    jobs.j[4] = {ff_w1, wt_f1, 256, 512, 16, 8, 4, 1536, 131072};
    jobs.j[5] = {ff_w2, wt_f2, 512, 256, 8, 16, 4, 2048, 131072};
    jobs.j[6] = {pool_w, wt_p, 256, 256, 8, 8, 1, 2560, 65536};
    setup_all_k<<<4420, 256, 0, stream>>>(jobs, rb_w1, rb_b1, rb_w2, rb_b2, tbl2,
                                          node_idx, mask, emb, x, ln1_g, ln1_b, hb);
  }

  for (int l = 0; l < L_; l++) {
    const float* qb = qkv_b + (size_t)l * 3 * H_;
    const float* ob = out_b + (size_t)l * H_;
    const float* gb1 = gate_b1 + (size_t)l * H_;
    const float* gb2 = gate_b2 + (size_t)l * H_;
    const float* fb1 = ff_b1 + (size_t)l * 2 * H_;
    const float* fb2 = ff_b2 + (size_t)l * H_;
    u16* wqg = wt_qg + (size_t)l * 1024 * 256;
    u16* wo = wt_out + (size_t)l * 256 * 256;
    u16* wg2 = wt_g2 + (size_t)l * 256 * 256;
    u16* wf1 = wt_f1 + (size_t)l * 512 * 256;
    u16* wf2 = wt_f2 + (size_t)l * 256 * 512;

    // qgb = hb @ [qkv_w | gate_w1] (+biases, silu on g1 cols)
    if (l == 0) {
      qkv_bias_k<<<2688, 256, 0, stream>>>(hb, wqg, qb, gb1, qgb, positions, mask, tbl2,
                                           biasb);
    } else {
      mgemm_k<3, false, false, true><<<dim3(16, 24), 256, 0, stream>>>(
          hb, wqg, qb, nullptr, qgb, 256, 1024, 256, nullptr, gb1);
    }
    // [attn(qgb, biasb[l]) -> ctx]  ||  [g2 = g1 @ gate_w2 + gate_b2]
    attn_g2_k<<<480, 256, 0, stream>>>(qgb, biasb + (size_t)l * bias_lstride, ctx,
                                       wg2, gb2, g2);
    // x += bf16(ctx*sigmoid(g2)) @ out_w + out_b ; hb = bf16(LN2(x))
    glngemm_k<true><<<24, 256, 0, stream>>>(ctx, wo, ob, g2, x, hb,
                                            ln2_g + l * H_, ln2_b + l * H_, 256, 256);
    // ffb = bf16(gelu(hb @ ff_w1 + ff_b1))
    mgemm_k<2, false, false, true><<<dim3(8, 24), 256, 0, stream>>>(
        hb, wf1, fb1, nullptr, ffb, 256, 512, 256, nullptr, nullptr);
    // x += ffb @ ff_w2 + ff_b2 ; hb = bf16(LN_next(x))  (pool LN on last layer)
    const float* nlg = (l < 3) ? (ln1_g + (l + 1) * H_) : pool_g;
    const float* nlb = (l < 3) ? (ln1_b + (l + 1) * H_) : pool_beta;
    glngemm_k<false><<<24, 256, 0, stream>>>(ffb, wf2, fb2, nullptr, x, hb,
                                             nlg, nlb, 512, 512);
  }

  // pooling head: ctx = silu(hb @ pool_w + pool_b)
  mgemm_k<1, false, false, false><<<dim3(4, 24), 256, 0, stream>>>(
      hb, wt_p, pool_b, nullptr, ctx, 256, 256, 256, nullptr, nullptr);
  energy_k<<<B_, 256, 0, stream>>>(ctx, mask, eh_w, eh_b, eout);
}

// Round 18
// 272.815 us; speedup vs baseline: 1.3081x; 1.3081x over previous
//
#include <hip/hip_runtime.h>
#include <hip/hip_bf16.h>
#include <math.h>

// Problem constants (hardcoded from reference)
constexpr int B_ = 4, N_ = 384, H_ = 256, NH_ = 8, DD_ = 32, L_ = 4;
constexpr int M_ = B_ * N_;          // 1536 node rows
constexpr float CUT = 5.0f;
constexpr float PI_ = 3.14159265358979323846f;
constexpr float INVSC = 0.17677669529663687f;  // 1/sqrt(32)
constexpr int TBL_N = 4096;
constexpr int TBL_STRIDE = 4098;

typedef __attribute__((ext_vector_type(8))) short short8;
typedef __attribute__((ext_vector_type(4))) float f32x4;
typedef __attribute__((ext_vector_type(4))) unsigned short u16x4;
using u16 = unsigned short;

__device__ __forceinline__ u16 f2b(float f) {
  __hip_bfloat16 h = __float2bfloat16(f);
  return *reinterpret_cast<u16*>(&h);
}
__device__ __forceinline__ float b2f(u16 u) {
  __hip_bfloat16 h;
  *reinterpret_cast<u16*>(&h) = u;
  return __bfloat162float(h);
}

__device__ __forceinline__ float wave_sum(float v) {
#pragma unroll
  for (int s = 1; s < 64; s <<= 1) v += __shfl_xor(v, s);
  return v;
}

// ---------------- device bodies ----------------

// per-edge bias (all 4 layers' tables), dist computed inline
__device__ __forceinline__ void bias_item(const float* __restrict__ pos,
                                          const float* __restrict__ mask,
                                          const float* __restrict__ tbl2,
                                          u16* __restrict__ biasb, int e) {
  int j = e % N_;
  int t = e / N_;
  int i = t % N_;
  int b = t / N_;
  float mi = mask[b * N_ + i], mj = mask[b * N_ + j];
  const float* pi = pos + (size_t)(b * N_ + i) * 3;
  const float* pj = pos + (size_t)(b * N_ + j) * 3;
  float dx = pi[0] - pj[0] + 1e-9f;
  float dy = pi[1] - pj[1] + 1e-9f;
  float dz = pi[2] - pj[2] + 1e-9f;
  float d = sqrtf(dx * dx + dy * dy + dz * dz);
  bool edge = (mi > 0.f && mj > 0.f) && (d <= CUT);
  size_t plane = (size_t)N_ * N_;
  size_t obase = (size_t)b * NH_ * plane + (size_t)i * N_ + j;
  size_t lstride = (size_t)B_ * NH_ * plane;
  if (edge) {
    int ixrow;
    float fr;
    if (i == j) {
      ixrow = TBL_N + 1;
      fr = 0.f;
    } else {
      float u = d * ((float)TBL_N / CUT);
      int ix = (int)u;
      ix = ix > TBL_N - 1 ? TBL_N - 1 : ix;
      fr = u - (float)ix;
      ixrow = ix;
    }
    const float4* r0 = (const float4*)(tbl2 + (size_t)ixrow * 32);
    const float4* r1 = (const float4*)(tbl2 + (size_t)(ixrow + 1) * 32);
    float4 a0[8], a1[8];
#pragma unroll
    for (int q = 0; q < 8; q++) {
      a0[q] = r0[q];
      a1[q] = r1[q];
    }
    float w0 = 1.f - fr;
#pragma unroll
    for (int q = 0; q < 8; q++) {
      float v0[4] = {a0[q].x, a0[q].y, a0[q].z, a0[q].w};
      float v1[4] = {a1[q].x, a1[q].y, a1[q].z, a1[q].w};
#pragma unroll
      for (int c = 0; c < 4; c++) {
        int lh = q * 4 + c;
        int l = lh >> 3, h = lh & 7;
        float v = v0[c] * w0 + v1[c] * fr;
        biasb[(size_t)l * lstride + obase + (size_t)h * plane] = f2b(v);
      }
    }
  } else {
#pragma unroll
    for (int lh = 0; lh < 32; lh++) {
      int l = lh >> 3, h = lh & 7;
      biasb[(size_t)l * lstride + obase + (size_t)h * plane] = 0xFF80;  // -inf
    }
  }
}

// ---------------- combined setup kernel ----------------
// blocks [0,260): bias-table; [260,2884): weight transposes; [2884,4420): embed+LN1(l0)
struct TrJob {
  const float* src;
  u16* dst;
  int K, N, nx, ny, nz, base, dstride;
};
struct TrJobs {
  TrJob j[7];
};
__global__ __launch_bounds__(256) void setup_all_k(TrJobs jobs,
                                                   const float* __restrict__ rb_w1,
                                                   const float* __restrict__ rb_b1,
                                                   const float* __restrict__ rb_w2,
                                                   const float* __restrict__ rb_b2,
                                                   float* __restrict__ tbl2,
                                                   const int* __restrict__ nidx,
                                                   const float* __restrict__ mask,
                                                   const float* __restrict__ emb,
                                                   float* __restrict__ X,
                                                   const float* __restrict__ l1g,
                                                   const float* __restrict__ l1b,
                                                   u16* __restrict__ HB) {
  __shared__ float sfA[64][32];
  __shared__ float hbA[64][260];
  __shared__ float t[32][33];
  __shared__ float sw[8];
  int bid = blockIdx.x;
  int tid = threadIdx.x;
  if (bid < 260) {
    constexpr int TT = 64;
    int l = bid / 65;
    int t0 = (bid % 65) * TT;
#pragma unroll
    for (int m = 0; m < 8; m++) {
      int idx = m * 256 + tid;
      int tl = idx >> 5, k = idx & 31;
      int tt = t0 + tl;
      float d = (tt <= TBL_N) ? (tt * (CUT / (float)TBL_N)) : 1.7320508075688772e-9f;
      float ang = PI_ * (k + 1) * d * (1.f / CUT);
      sfA[tl][k] = sinf(ang) / (d + 1e-6f);
    }
    __syncthreads();
    float w1c[32];
    const float* w1 = rb_w1 + (size_t)l * DD_ * H_;
#pragma unroll
    for (int k = 0; k < 32; k++) w1c[k] = w1[k * H_ + tid];
    float b1v = rb_b1[l * H_ + tid];
    for (int tl = 0; tl < TT; tl++) {
      float pre = b1v;
      const float4* sfp = (const float4*)sfA[tl];
#pragma unroll
      for (int kq = 0; kq < 8; kq++) {
        float4 s4 = sfp[kq];
        pre += s4.x * w1c[kq * 4] + s4.y * w1c[kq * 4 + 1] + s4.z * w1c[kq * 4 + 2] +
               s4.w * w1c[kq * 4 + 3];
      }
      hbA[tl][tid] = pre / (1.f + __expf(-pre));
    }
    __syncthreads();
    const float* w2 = rb_w2 + (size_t)l * H_ * NH_;
    int o = tid & 7;
    float b2v = rb_b2[l * NH_ + o];
#pragma unroll
    for (int half = 0; half < 2; half++) {
      int tl = (tid >> 3) + half * 32;
      float acc = b2v;
      const float4* hp = (const float4*)hbA[tl];
#pragma unroll 4
      for (int hq = 0; hq < 64; hq++) {
        float4 h4 = hp[hq];
        acc += h4.x * w2[(hq * 4 + 0) * NH_ + o] + h4.y * w2[(hq * 4 + 1) * NH_ + o] +
               h4.z * w2[(hq * 4 + 2) * NH_ + o] + h4.w * w2[(hq * 4 + 3) * NH_ + o];
      }
      int tt = t0 + tl;
      if (tt <= TBL_STRIDE) tbl2[(size_t)tt * 32 + l * NH_ + o] = acc;
    }
  } else if (bid < 2884) {
    int tb = bid - 260;
    int ji = 0;
#pragma unroll
    for (int q = 1; q < 7; q++)
      if (tb >= jobs.j[q].base) ji = q;
    const TrJob& J = jobs.j[ji];
    int local = tb - J.base;
    int z = local / (J.nx * J.ny);
    int r2 = local % (J.nx * J.ny);
    int ky = r2 / J.nx, kx = r2 % J.nx;
    int n0 = kx * 32, k0 = ky * 32;
    const float* s = J.src + (size_t)z * J.K * J.N;
    u16* d = J.dst + (size_t)z * J.dstride;
    int r = tid >> 3, c4 = (tid & 7) * 4;
    float4 v = *(const float4*)(s + (size_t)(k0 + r) * J.N + n0 + c4);
    t[r][c4 + 0] = v.x;
    t[r][c4 + 1] = v.y;
    t[r][c4 + 2] = v.z;
    t[r][c4 + 3] = v.w;
    __syncthreads();
    u16x4 o;
    o[0] = f2b(t[c4 + 0][r]);
    o[1] = f2b(t[c4 + 1][r]);
    o[2] = f2b(t[c4 + 2][r]);
    o[3] = f2b(t[c4 + 3][r]);
    *(u16x4*)(d + (size_t)(n0 + r) * J.K + k0 + c4) = o;
  } else {
    // ---- embed + LN1(layer0): one row per block ----
    int row = bid - 2884;
    float mb = mask[row] > 0.f ? 1.f : 0.f;
    float v = emb[nidx[row] * H_ + tid] * mb;
    X[(size_t)row * H_ + tid] = v;
    float s = wave_sum(v);
    float q = wave_sum(v * v);
    int wv = tid >> 6, ln = tid & 63;
    if (ln == 0) {
      sw[wv] = s;
      sw[4 + wv] = q;
    }
    __syncthreads();
    float ts = sw[0] + sw[1] + sw[2] + sw[3];
    float tq = sw[4] + sw[5] + sw[6] + sw[7];
    float m = ts * (1.f / 256.f);
    float rs = rsqrtf(tq * (1.f / 256.f) - m * m + 1e-5f);
    HB[(size_t)row * H_ + tid] = f2b((v - m) * rs * l1g[tid] + l1b[tid]);
  }
}

// ---------------- LayerNorm (row of 256) -> bf16 output ----------------
__global__ __launch_bounds__(256) void ln_k(const float* __restrict__ X,
                                            const float* __restrict__ g,
                                            const float* __restrict__ bta,
                                            u16* __restrict__ O) {
  int wave = threadIdx.x >> 6, lane = threadIdx.x & 63;
  int row = blockIdx.x * 4 + wave;
  const float* xr = X + (size_t)row * H_;
  float4 v = *(const float4*)(xr + lane * 4);
  float s = v.x + v.y + v.z + v.w;
  s = wave_sum(s);
  float m = s * (1.f / H_);
  float dx = v.x - m, dy = v.y - m, dz = v.z - m, dw = v.w - m;
  float vs = dx * dx + dy * dy + dz * dz + dw * dw;
  vs = wave_sum(vs);
  float rs = rsqrtf(vs * (1.f / H_) + 1e-5f);
  float4 gg = *(const float4*)(g + lane * 4);
  float4 bb = *(const float4*)(bta + lane * 4);
  u16x4 o;
  o[0] = f2b(dx * rs * gg.x + bb.x);
  o[1] = f2b(dy * rs * gg.y + bb.y);
  o[2] = f2b(dz * rs * gg.z + bb.z);
  o[3] = f2b(dw * rs * gg.w + bb.w);
  *(u16x4*)(O + (size_t)row * H_ + lane * 4) = o;
}

// ---------------- bf16 MFMA GEMM body (device) ----------------
// C[M,Nc] = act(A'[M,K] @ W[K,Nc] + bias) (+resid); A' = PRE ? bf16(Af32*sigmoid(G)) : A
// ACT: 0 none, 1 silu, 2 gelu, 3 = plain bias col<768 / silu+bias2 col>=768.
template <int ACT, bool RES, bool PRE, bool OBF>
__device__ __forceinline__ void mgemm_body(u16* __restrict__ As, u16* __restrict__ Bs,
                                           const void* __restrict__ Av,
                                           const u16* __restrict__ WT,
                                           const float* __restrict__ bias,
                                           const float* __restrict__ resid,
                                           void* __restrict__ Cv, int K, int Nc,
                                           int lda, const float* __restrict__ G,
                                           const float* __restrict__ bias2,
                                           int m0, int n0) {
  const int tid = threadIdx.x;
  const int wave = tid >> 6, lane = tid & 63;
  const int wr = wave >> 1, wc = wave & 1, lr = lane & 15, lg = lane >> 4;
  f32x4 acc[2][2] = {};
  const int srow = tid >> 2, sp = tid & 3;
  for (int k0 = 0; k0 < K; k0 += 128) {
#pragma unroll
    for (int s4 = 0; s4 < 4; s4++) {
      int s = sp * 4 + s4;
      int phys = s ^ (srow & 15);
      if (PRE) {
        const float* ap = (const float*)Av + (size_t)(m0 + srow) * lda + k0 + s * 8;
        const float* gp = G + (size_t)(m0 + srow) * lda + k0 + s * 8;
        float4 a0 = *(const float4*)ap;
        float4 a1 = *(const float4*)(ap + 4);
        float4 g0 = *(const float4*)gp;
        float4 g1 = *(const float4*)(gp + 4);
        short8 vv;
        vv[0] = (short)f2b(a0.x / (1.f + __expf(-g0.x)));
        vv[1] = (short)f2b(a0.y / (1.f + __expf(-g0.y)));
        vv[2] = (short)f2b(a0.z / (1.f + __expf(-g0.z)));
        vv[3] = (short)f2b(a0.w / (1.f + __expf(-g0.w)));
        vv[4] = (short)f2b(a1.x / (1.f + __expf(-g1.x)));
        vv[5] = (short)f2b(a1.y / (1.f + __expf(-g1.y)));
        vv[6] = (short)f2b(a1.z / (1.f + __expf(-g1.z)));
        vv[7] = (short)f2b(a1.w / (1.f + __expf(-g1.w)));
        *(short8*)&As[srow * 128 + phys * 8] = vv;
      } else {
        const u16* Ab = (const u16*)Av;
        short8 v = *(const short8*)(Ab + (size_t)(m0 + srow) * lda + k0 + s * 8);
        *(short8*)&As[srow * 128 + phys * 8] = v;
      }
      short8 w = *(const short8*)(WT + (size_t)(n0 + srow) * K + k0 + s * 8);
      *(short8*)&Bs[srow * 128 + phys * 8] = w;
    }
    __syncthreads();
#pragma unroll
    for (int kk = 0; kk < 4; kk++) {
      int slot = kk * 4 + lg;
      short8 af[2], bf_[2];
#pragma unroll
      for (int i = 0; i < 2; i++) {
        int row = wr * 32 + i * 16 + lr;
        af[i] = *(const short8*)&As[row * 128 + (slot ^ (row & 15)) * 8];
      }
#pragma unroll
      for (int j = 0; j < 2; j++) {
        int row = wc * 32 + j * 16 + lr;
        bf_[j] = *(const short8*)&Bs[row * 128 + (slot ^ (row & 15)) * 8];
      }
#pragma unroll
      for (int i = 0; i < 2; i++)
#pragma unroll
        for (int j = 0; j < 2; j++)
          acc[i][j] = __builtin_amdgcn_mfma_f32_16x16x32_bf16(af[i], bf_[j], acc[i][j], 0, 0, 0);
    }
    __syncthreads();
  }
#pragma unroll
  for (int i = 0; i < 2; i++)
#pragma unroll
    for (int j = 0; j < 2; j++)
#pragma unroll
      for (int rg = 0; rg < 4; rg++) {
        int row = m0 + wr * 32 + i * 16 + lg * 4 + rg;
        int col = n0 + wc * 32 + j * 16 + lr;
        float v;
        if (ACT == 3) {
          float bv = (col < 768) ? bias[col] : bias2[col - 768];
          v = acc[i][j][rg] + bv;
          if (col >= 768) v = v / (1.f + __expf(-v));
        } else {
          v = acc[i][j][rg] + bias[col];
          if (ACT == 1) v = v / (1.f + __expf(-v));
          if (ACT == 2) v = 0.5f * v * (1.f + erff(v * 0.70710678118654752f));
        }
        if (RES) v += resid[(size_t)row * Nc + col];
        if (OBF)
          ((u16*)Cv)[(size_t)row * Nc + col] = f2b(v);
        else
          ((float*)Cv)[(size_t)row * Nc + col] = v;
      }
}

template <int ACT, bool RES, bool PRE, bool OBF>
__global__ __launch_bounds__(256) void mgemm_k(const void* __restrict__ Av,
                                               const u16* __restrict__ WT,
                                               const float* __restrict__ bias,
                                               const float* __restrict__ resid,
                                               void* __restrict__ Cv, int K, int Nc,
                                               int lda, const float* __restrict__ G,
                                               const float* __restrict__ bias2) {
  __shared__ u16 As[64 * 128];
  __shared__ u16 Bs[64 * 128];
  mgemm_body<ACT, RES, PRE, OBF>(As, Bs, Av, WT, bias, resid, Cv, K, Nc, lda, G, bias2,
                                 blockIdx.y * 64, blockIdx.x * 64);
}

// ---------------- layer-0 qkv-gate GEMM + bias-tensor build (one launch) ----------
__global__ __launch_bounds__(256) void qkv_bias_k(const u16* __restrict__ hb,
                                                  const u16* __restrict__ wqg,
                                                  const float* __restrict__ qb,
                                                  const float* __restrict__ gb1,
                                                  u16* __restrict__ qgb,
                                                  const float* __restrict__ pos,
                                                  const float* __restrict__ mask,
                                                  const float* __restrict__ tbl2,
                                                  u16* __restrict__ biasb) {
  __shared__ u16 As[64 * 128];
  __shared__ u16 Bs[64 * 128];
  int bid = blockIdx.x;
  if (bid < 384) {
    mgemm_body<3, false, false, true>(As, Bs, hb, wqg, qb, nullptr, qgb, 256, 1024, 256,
                                      nullptr, gb1, (bid >> 4) * 64, (bid & 15) * 64);
  } else {
    bias_item(pos, mask, tbl2, biasb, (bid - 384) * 256 + threadIdx.x);
  }
}

// ---------------- MFMA fused attention body (device) ----------------
__device__ __forceinline__ void attn_body(u16* __restrict__ FragQ, u16* __restrict__ FragK,
                                          u16* __restrict__ FragV, float* __restrict__ smax,
                                          float* __restrict__ ssum,
                                          const u16* __restrict__ qkv,
                                          const u16* __restrict__ biasb,
                                          float* __restrict__ ctx, int qs,
                                          int it, int hh, int b) {
  u16* FragP = FragK;
  float* pbuf = (float*)FragV;
  const int i0 = it * 32;
  const int tid = threadIdx.x;
  const size_t bb = (size_t)b * N_;

  if (tid < 128) {
    int q = tid >> 2, dc = tid & 3;
    short8 v = *(const short8*)(qkv + (bb + i0 + q) * qs + hh * 32 + dc * 8);
    *(short8*)&FragQ[(((q >> 4) * 64) + (q & 15) + 16 * dc) * 8] = v;
  }
#pragma unroll
  for (int m = 0; m < 6; m++) {
    int idx = m * 256 + tid;
    int key = idx >> 2, dc = idx & 3;
    const u16* kb = qkv + (bb + key) * qs + 256 + hh * 32 + dc * 8;
    short8 kv = *(const short8*)kb;
    *(short8*)&FragK[(((key >> 4) * 64) + (key & 15) + 16 * dc) * 8] = kv;
    short8 vv = *(const short8*)(kb + 256);
    int kc = key >> 5, sub = (key >> 3) & 3, kj = key & 7;
#pragma unroll
    for (int j = 0; j < 8; j++) {
      int d = dc * 8 + j;
      FragV[(((kc * 2 + (d >> 4)) * 64) + (d & 15) + 16 * sub) * 8 + kj] = (u16)vv[j];
    }
  }
  __syncthreads();  // #0

  const int wave = tid >> 6, lane = tid & 63;
  const int rh = wave & 1, kh = wave >> 1;
  const int g = lane >> 4, c = lane & 15;
  const u16* bptr = biasb + (size_t)(b * NH_ + hh) * N_ * N_;

  short8 qf = *(const short8*)&FragQ[(rh * 64 + lane) * 8];
  f32x4 sc[12];
#pragma unroll
  for (int t = 0; t < 12; t++) {
    int T = kh * 12 + t;
    short8 kf = *(const short8*)&FragK[(T * 64 + lane) * 8];
    f32x4 z = {0.f, 0.f, 0.f, 0.f};
    sc[t] = __builtin_amdgcn_mfma_f32_16x16x32_bf16(qf, kf, z, 0, 0, 0);
    int key = 16 * T + c;
#pragma unroll
    for (int reg = 0; reg < 4; reg++) {
      int row = i0 + 16 * rh + 4 * g + reg;
      float bv = b2f(bptr[(size_t)row * N_ + key]);
      sc[t][reg] = sc[t][reg] * INVSC + bv;
    }
  }
  float mx[4];
#pragma unroll
  for (int reg = 0; reg < 4; reg++) {
    float m = sc[0][reg];
#pragma unroll
    for (int t = 1; t < 12; t++) m = fmaxf(m, sc[t][reg]);
#pragma unroll
    for (int s = 1; s < 16; s <<= 1) m = fmaxf(m, __shfl_xor(m, s));
    mx[reg] = m;
  }
  if (c == 0) {
#pragma unroll
    for (int reg = 0; reg < 4; reg++) smax[kh * 32 + 16 * rh + 4 * g + reg] = mx[reg];
  }
  __syncthreads();  // #1
  float sm[4];
#pragma unroll
  for (int reg = 0; reg < 4; reg++) {
    float M = fmaxf(smax[16 * rh + 4 * g + reg], smax[32 + 16 * rh + 4 * g + reg]);
    float s = 0.f;
#pragma unroll
    for (int t = 0; t < 12; t++) {
      float p = __expf(sc[t][reg] - M);
      sc[t][reg] = p;
      s += p;
    }
    sm[reg] = s;
  }
#pragma unroll
  for (int reg = 0; reg < 4; reg++) {
#pragma unroll
    for (int s = 1; s < 16; s <<= 1) sm[reg] += __shfl_xor(sm[reg], s);
  }
  if (c == 0) {
#pragma unroll
    for (int reg = 0; reg < 4; reg++) ssum[kh * 32 + 16 * rh + 4 * g + reg] = sm[reg];
  }
#pragma unroll
  for (int t = 0; t < 12; t++) {
    int T = kh * 12 + t;
    int kc = T >> 1;
    int sub = (2 * T + (c >> 3)) & 3;
#pragma unroll
    for (int reg = 0; reg < 4; reg++) {
      FragP[((rh * 12 + kc) * 64 + (4 * g + reg) + 16 * sub) * 8 + (c & 7)] =
          f2b(sc[t][reg]);
    }
  }
  __syncthreads();  // #2
  float Ls[4];
#pragma unroll
  for (int reg = 0; reg < 4; reg++)
    Ls[reg] = ssum[16 * rh + 4 * g + reg] + ssum[32 + 16 * rh + 4 * g + reg];

  f32x4 pcc[2] = {};
#pragma unroll
  for (int t = 0; t < 6; t++) {
    int kc = kh * 6 + t;
    short8 pf = *(const short8*)&FragP[((rh * 12 + kc) * 64 + lane) * 8];
#pragma unroll
    for (int nh = 0; nh < 2; nh++) {
      short8 vf = *(const short8*)&FragV[((kc * 2 + nh) * 64 + lane) * 8];
      pcc[nh] = __builtin_amdgcn_mfma_f32_16x16x32_bf16(pf, vf, pcc[nh], 0, 0, 0);
    }
  }
  __syncthreads();  // #3
  if (kh == 1) {
#pragma unroll
    for (int nh = 0; nh < 2; nh++)
#pragma unroll
      for (int reg = 0; reg < 4; reg++)
        pbuf[rh * 512 + (4 * g + reg) * 32 + nh * 16 + c] = pcc[nh][reg];
  }
  __syncthreads();  // #4
  if (kh == 0) {
#pragma unroll
    for (int nh = 0; nh < 2; nh++)
#pragma unroll
      for (int reg = 0; reg < 4; reg++) {
        float v = pcc[nh][reg] + pbuf[rh * 512 + (4 * g + reg) * 32 + nh * 16 + c];
        int row = i0 + 16 * rh + 4 * g + reg;
        ctx[(bb + row) * H_ + hh * 32 + nh * 16 + c] = v / Ls[reg];
      }
  }
}

// ---------------- merged attention + gate2-GEMM launch ----------------
__global__ __launch_bounds__(256) void attn_g2_k(const u16* __restrict__ qkv,
                                                 const u16* __restrict__ biasb,
                                                 float* __restrict__ ctx,
                                                 const u16* __restrict__ wg2,
                                                 const float* __restrict__ gb2,
                                                 float* __restrict__ g2) {
  __shared__ __align__(16) u16 SMEM[(2 + 24 + 24) * 64 * 8];  // 50 KB
  __shared__ float sred[2 * 32 * 2];                          // smax | ssum
  int bid = blockIdx.x;
  if (bid < 384) {
    int it = bid % 12;
    int t = bid / 12;
    attn_body(SMEM, SMEM + 1024, SMEM + 1024 + 12288, sred, sred + 64,
              qkv, biasb, ctx, 1024, it, t % NH_, t / NH_);
  } else {
    int g = bid - 384;  // 0..95 ; n0 = (g&3)*64, m0 = (g>>2)*64
    mgemm_body<0, false, false, false>(SMEM, SMEM + 8192, (const void*)(qkv + 768), wg2,
                                       gb2, nullptr, g2, 256, 256, 1024, nullptr,
                                       nullptr, (g >> 2) * 64, (g & 3) * 64);
  }
}

// ---------------- energy: masked mean over nodes then dot with eh_w ----------------
__global__ __launch_bounds__(256) void energy_k(const float* __restrict__ p2,
                                                const float* __restrict__ mask,
                                                const float* __restrict__ ehw,
                                                const float* __restrict__ ehb,
                                                float* __restrict__ out) {
  int b = blockIdx.x, h = threadIdx.x;
  float s = 0.f, cnt = 0.f;
#pragma unroll 4
  for (int i = 0; i < N_; i++) {
    float m = mask[b * N_ + i] > 0.f ? 1.f : 0.f;
    s += p2[(size_t)(b * N_ + i) * H_ + h] * m;
    cnt += m;
  }
  float val = s * ehw[h];
  __shared__ float red[256];
  red[h] = val;
  __syncthreads();
  for (int st = 128; st > 0; st >>= 1) {
    if (h < st) red[h] += red[h + st];
    __syncthreads();
  }
  if (h == 0) {
    float c = cnt < 1.f ? 1.f : cnt;
    out[b] = red[0] / c + ehb[0];
  }
}

extern "C" void kernel_launch(void* const* d_in, const int* in_sizes, int n_in,
                              void* d_out, int out_size, void* d_ws, size_t ws_size,
                              hipStream_t stream) {
  const int* node_idx = (const int*)d_in[0];
  const float* positions = (const float*)d_in[1];
  const float* mask = (const float*)d_in[2];
  const float* emb = (const float*)d_in[3];
  const float* ln1_g = (const float*)d_in[4];
  const float* ln1_b = (const float*)d_in[5];
  const float* qkv_w = (const float*)d_in[6];
  const float* qkv_b = (const float*)d_in[7];
  const float* out_w = (const float*)d_in[8];
  const float* out_b = (const float*)d_in[9];
  const float* rb_w1 = (const float*)d_in[10];
  const float* rb_b1 = (const float*)d_in[11];
  const float* rb_w2 = (const float*)d_in[12];
  const float* rb_b2 = (const float*)d_in[13];
  const float* gate_w1 = (const float*)d_in[14];
  const float* gate_b1 = (const float*)d_in[15];
  const float* gate_w2 = (const float*)d_in[16];
  const float* gate_b2 = (const float*)d_in[17];
  const float* ln2_g = (const float*)d_in[18];
  const float* ln2_b = (const float*)d_in[19];
  const float* ff_w1 = (const float*)d_in[20];
  const float* ff_b1 = (const float*)d_in[21];
  const float* ff_w2 = (const float*)d_in[22];
  const float* ff_b2 = (const float*)d_in[23];
  const float* pool_g = (const float*)d_in[24];
  const float* pool_beta = (const float*)d_in[25];
  const float* pool_w = (const float*)d_in[26];
  const float* pool_b = (const float*)d_in[27];
  const float* eh_w = (const float*)d_in[28];
  const float* eh_b = (const float*)d_in[29];
  float* eout = (float*)d_out;

  // workspace layout (bytes)
  char* W8 = (char*)d_ws;
  float* x = (float*)(W8 + 0);              // 1572864 B (M x 256 f32)
  u16* qgb = (u16*)(W8 + 1572864);          // 3145728 B (M x 1024 bf16: q|k|v|g1)
  float* ctx = (float*)(W8 + 4718592);      // 1572864 B
  float* g2 = (float*)(W8 + 6291456);       // 1572864 B
  u16* hb = (u16*)(W8 + 7864320);           // 786432 B  (M x 256 bf16)
  u16* ffb = (u16*)(W8 + 8650752);          // 1572864 B (M x 512 bf16)
  float* tbl2 = (float*)(W8 + 12582912);    // 524672 B (t-major)
  u16* wt = (u16*)(W8 + 13631488);          // 5373952 B
  u16* wt_qg = wt;                  // 4 x 1024 x 256
  u16* wt_out = wt + 1048576;       // 4 x 256 x 256
  u16* wt_g2 = wt + 1310720;
  u16* wt_f1 = wt + 1572864;        // 4 x 512 x 256
  u16* wt_f2 = wt + 2097152;        // 4 x 256 x 512
  u16* wt_p = wt + 2621440;         // 256 x 256
  u16* biasb = (u16*)(W8 + 19005440);       // 4 x 9437184 B ([l][b][h][i][j] bf16)
  const size_t bias_lstride = (size_t)B_ * NH_ * N_ * N_;

  // ---- setup: table + transposes + embed+LN1(l0) in ONE launch ----
  {
    TrJobs jobs;
    jobs.j[0] = {qkv_w, wt_qg, 256, 768, 24, 8, 4, 0, 262144};
    jobs.j[1] = {gate_w1, wt_qg + 768 * 256, 256, 256, 8, 8, 4, 768, 262144};
    jobs.j[2] = {out_w, wt_out, 256, 256, 8, 8, 4, 1024, 65536};
    jobs.j[3] = {gate_w2, wt_g2, 256, 256, 8, 8, 4, 1280, 65536};
    jobs.j[4] = {ff_w1, wt_f1, 256, 512, 16, 8, 4, 1536, 131072};
    jobs.j[5] = {ff_w2, wt_f2, 512, 256, 8, 16, 4, 2048, 131072};
    jobs.j[6] = {pool_w, wt_p, 256, 256, 8, 8, 1, 2560, 65536};
    setup_all_k<<<4420, 256, 0, stream>>>(jobs, rb_w1, rb_b1, rb_w2, rb_b2, tbl2,
                                          node_idx, mask, emb, x, ln1_g, ln1_b, hb);
  }

  for (int l = 0; l < L_; l++) {
    const float* qb = qkv_b + (size_t)l * 3 * H_;
    const float* ob = out_b + (size_t)l * H_;
    const float* gb1 = gate_b1 + (size_t)l * H_;
    const float* gb2 = gate_b2 + (size_t)l * H_;
    const float* fb1 = ff_b1 + (size_t)l * 2 * H_;
    const float* fb2 = ff_b2 + (size_t)l * H_;
    u16* wqg = wt_qg + (size_t)l * 1024 * 256;
    u16* wo = wt_out + (size_t)l * 256 * 256;
    u16* wg2 = wt_g2 + (size_t)l * 256 * 256;
    u16* wf1 = wt_f1 + (size_t)l * 512 * 256;
    u16* wf2 = wt_f2 + (size_t)l * 256 * 512;

    // qgb = hb @ [qkv_w | gate_w1] (+biases, silu on g1 cols)
    if (l == 0) {
      qkv_bias_k<<<2688, 256, 0, stream>>>(hb, wqg, qb, gb1, qgb, positions, mask, tbl2,
                                           biasb);
    } else {
      mgemm_k<3, false, false, true><<<dim3(16, 24), 256, 0, stream>>>(
          hb, wqg, qb, nullptr, qgb, 256, 1024, 256, nullptr, gb1);
    }
    // [attn(qgb, biasb[l]) -> ctx]  ||  [g2 = g1 @ gate_w2 + gate_b2]
    attn_g2_k<<<480, 256, 0, stream>>>(qgb, biasb + (size_t)l * bias_lstride, ctx,
                                       wg2, gb2, g2);
    // x = x + bf16(ctx * sigmoid(g2)) @ out_w + out_b
    mgemm_k<0, true, true, false><<<dim3(4, 24), 256, 0, stream>>>(
        ctx, wo, ob, x, x, 256, 256, 256, g2, nullptr);
    // hb = bf16(LN2(x))
    ln_k<<<M_ / 4, 256, 0, stream>>>(x, ln2_g + l * H_, ln2_b + l * H_, hb);
    // ffb = bf16(gelu(hb @ ff_w1 + ff_b1))
    mgemm_k<2, false, false, true><<<dim3(8, 24), 256, 0, stream>>>(
        hb, wf1, fb1, nullptr, ffb, 256, 512, 256, nullptr, nullptr);
    // x = x + ffb @ ff_w2 + ff_b2
    mgemm_k<0, true, false, false><<<dim3(4, 24), 256, 0, stream>>>(
        ffb, wf2, fb2, x, x, 512, 256, 512, nullptr, nullptr);
    // hb = bf16(LN_next(x))  (LN1 of next layer; pool-LN after last layer)
    const float* nlg = (l < 3) ? (ln1_g + (l + 1) * H_) : pool_g;
    const float* nlb = (l < 3) ? (ln1_b + (l + 1) * H_) : pool_beta;
    ln_k<<<M_ / 4, 256, 0, stream>>>(x, nlg, nlb, hb);
  }

  // pooling head: ctx = silu(hb @ pool_w + pool_b)
  mgemm_k<1, false, false, false><<<dim3(4, 24), 256, 0, stream>>>(
      hb, wt_p, pool_b, nullptr, ctx, 256, 256, 256, nullptr, nullptr);
  energy_k<<<B_, 256, 0, stream>>>(ctx, mask, eh_w, eh_b, eout);
}